// Round 1
// baseline (212.646 us; speedup 1.0000x reference)
//
#include <hip/hip_runtime.h>
#include <hip/hip_fp16.h>

#define B_     4096
#define INE_   4096
#define INBR_  8192
#define D_     2048
#define KE_    50
#define KPAD_  52
#define CAP_   512

// ---------- helpers ----------
__device__ __forceinline__ unsigned packh2(float a, float b) {
  __half2 h = __floats2half2_rn(a, b);
  return __builtin_bit_cast(unsigned, h);
}
__device__ __forceinline__ float2 unpackh2(unsigned u) {
  __half2 h = __builtin_bit_cast(__half2, u);
  return __half22float2(h);
}

// ---------- K1: exact top-k per row via threshold filter + rank ----------
__global__ __launch_bounds__(256) void topk_kernel(
    const float* __restrict__ W, int k, int kpad, float hi, float t0,
    float vscale, unsigned* __restrict__ out_off, float* __restrict__ out_val)
{
  const int row = blockIdx.x;
  const int t   = threadIdx.x;
  const float* wr = W + (size_t)row * INE_;

  __shared__ float cval[CAP_];
  __shared__ int   ccol[CAP_];
  __shared__ int   scnt, swcnt;
  __shared__ int   red[4];

  // ---- threshold search (usually 1 iteration) ----
  float thr = t0;
  int M = 0;
  for (int attempt = 0; attempt < 8; ++attempt) {
    int local = 0;
    #pragma unroll
    for (int j = 0; j < 4; ++j) {
      float4 w4 = *reinterpret_cast<const float4*>(wr + 4 * (t + 256 * j));
      local += (w4.x > thr) + (w4.y > thr) + (w4.z > thr) + (w4.w > thr);
    }
    #pragma unroll
    for (int off = 32; off > 0; off >>= 1) local += __shfl_down(local, off);
    if ((t & 63) == 0) red[t >> 6] = local;
    __syncthreads();
    M = red[0] + red[1] + red[2] + red[3];
    __syncthreads();
    if (M >= k && M <= CAP_) break;
    if (M < k) thr = hi - (hi - thr) * 4.0f;   // widen window downward
    else       thr = hi - (hi - thr) * 0.5f;   // narrow (shouldn't trigger)
  }

  // ---- compaction ----
  if (t == 0) { scnt = 0; swcnt = 0; }
  __syncthreads();
  #pragma unroll
  for (int j = 0; j < 4; ++j) {
    int cbase = 4 * (t + 256 * j);
    float4 w4 = *reinterpret_cast<const float4*>(wr + cbase);
    float wv[4] = {w4.x, w4.y, w4.z, w4.w};
    #pragma unroll
    for (int q = 0; q < 4; ++q) {
      if (wv[q] > thr) {
        int p = atomicAdd(&scnt, 1);
        if (p < CAP_) { cval[p] = wv[q]; ccol[p] = cbase + q; }
      }
    }
  }
  __syncthreads();
  M = scnt < CAP_ ? scnt : CAP_;

  // ---- exact rank among candidates (ties -> lowest column index) ----
  for (int i = t; i < M; i += 256) {
    float wi = cval[i]; int ci = ccol[i];
    int rank = 0;
    for (int m = 0; m < M; ++m) {
      float wm = cval[m]; int cm = ccol[m];
      rank += (wm > wi || (wm == wi && cm < ci)) ? 1 : 0;
    }
    if (rank < k) {
      int p = atomicAdd(&swcnt, 1);
      unsigned c = (unsigned)ci;
      // pre-swizzled LDS byte offset: 16 * s(c), s(c) = (c>>2) | ((c&3)<<10)
      out_off[(size_t)row * kpad + p] = ((c >> 2) << 4) | ((c & 3u) << 14);
      out_val[(size_t)row * kpad + p] = wi * vscale;
    }
  }
  __syncthreads();
  int wc = swcnt;
  for (int q = wc + t; q < kpad; q += 256) {   // pad unused slots (harmless zeros)
    out_off[(size_t)row * kpad + q] = 0u;
    out_val[(size_t)row * kpad + q] = 0.0f;
  }
}

// ---------- K2: fused sparse-gather act computation ----------
// LDS layout: column c of the 8 staged rows lives at words [4*s(c) .. 4*s(c)+3],
// word p = half2(row 2p, row 2p+1).  s(c) = (c>>2) | ((c&3)<<10)  (bijective).
__device__ __forceinline__ void stage_rows(const float* __restrict__ src,
                                           unsigned* xs, int b0, int p, int Q) {
  const float* r0p = src + (size_t)(b0 + 2 * p)     * INE_;
  const float* r1p = src + (size_t)(b0 + 2 * p + 1) * INE_;
  #pragma unroll
  for (int m = 0; m < 8; ++m) {
    int c0 = 4 * Q + 512 * m;
    float4 fa = *reinterpret_cast<const float4*>(r0p + c0);
    float4 fb = *reinterpret_cast<const float4*>(r1p + c0);
    int wb = 4 * (Q + 128 * m) + p;
    xs[wb]          = packh2(fa.x, fb.x);
    xs[wb + 4096]   = packh2(fa.y, fb.y);
    xs[wb + 8192]   = packh2(fa.z, fb.z);
    xs[wb + 12288]  = packh2(fa.w, fb.w);
  }
}

#define GATH(R, OFF, WV) do {                                              \
    uint4 xq = *reinterpret_cast<const uint4*>(ldsb + (OFF));              \
    float2 f0 = unpackh2(xq.x), f1 = unpackh2(xq.y);                       \
    float2 f2 = unpackh2(xq.z), f3 = unpackh2(xq.w);                       \
    acc[R][0] = fmaf(f0.x, (WV), acc[R][0]);                               \
    acc[R][1] = fmaf(f0.y, (WV), acc[R][1]);                               \
    acc[R][2] = fmaf(f1.x, (WV), acc[R][2]);                               \
    acc[R][3] = fmaf(f1.y, (WV), acc[R][3]);                               \
    acc[R][4] = fmaf(f2.x, (WV), acc[R][4]);                               \
    acc[R][5] = fmaf(f2.y, (WV), acc[R][5]);                               \
    acc[R][6] = fmaf(f3.x, (WV), acc[R][6]);                               \
    acc[R][7] = fmaf(f3.y, (WV), acc[R][7]);                               \
  } while (0)

__global__ __launch_bounds__(512, 4) void fused_main(
    const float* __restrict__ xe, const float* __restrict__ xi,
    const float* __restrict__ xbr, const float* __restrict__ wblock,
    const unsigned* __restrict__ so_exc, const float* __restrict__ ve_exc,
    const unsigned* __restrict__ so_inh, const float* __restrict__ vi_inh,
    float* __restrict__ act, float* __restrict__ sums, float* __restrict__ sumsq)
{
  __shared__ unsigned xs[16384];          // 64 KiB
  const int t  = threadIdx.x;
  const int b0 = blockIdx.x * 8;
  const int p  = t & 3;
  const int Q  = t >> 2;

  float acc[4][8];
  #pragma unroll
  for (int r = 0; r < 4; ++r)
    #pragma unroll
    for (int b = 0; b < 8; ++b) acc[r][b] = 0.0f;

  const char* ldsb = reinterpret_cast<const char*>(xs);

  // ---- phase E: excitation (top-50 sparse) ----
  stage_rows(xe, xs, b0, p, Q);
  __syncthreads();
  #pragma unroll
  for (int r = 0; r < 4; ++r) {
    const int d = t + 512 * r;
    const uint4*  op = reinterpret_cast<const uint4*>(so_exc + (size_t)d * KPAD_);
    const float4* vp = reinterpret_cast<const float4*>(ve_exc + (size_t)d * KPAD_);
    #pragma unroll 2
    for (int ii = 0; ii < KPAD_ / 4; ++ii) {
      uint4  o = op[ii];
      float4 v = vp[ii];
      GATH(r, o.x, v.x);
      GATH(r, o.y, v.y);
      GATH(r, o.z, v.z);
      GATH(r, o.w, v.w);
    }
  }
  __syncthreads();

  // ---- phase I: inhibition (top-1 sparse, value pre-scaled by -50) ----
  stage_rows(xi, xs, b0, p, Q);
  __syncthreads();
  #pragma unroll
  for (int r = 0; r < 4; ++r) {
    const int d = t + 512 * r;
    unsigned o = so_inh[d];
    float    v = vi_inh[d];
    GATH(r, o, v);
  }

  // ---- phase BR: block-diagonal depolarization (streamed) ----
  #pragma unroll
  for (int r = 0; r < 4; ++r) {
    const int d = t + 512 * r;
    float4 wb4 = *reinterpret_cast<const float4*>(wblock + (size_t)d * (INBR_ + 4));
    #pragma unroll
    for (int b = 0; b < 8; ++b) {
      float4 xb4 = *reinterpret_cast<const float4*>(
          xbr + (size_t)(b0 + b) * INBR_ + 4 * d);
      acc[r][b] += xb4.x * wb4.x + xb4.y * wb4.y + xb4.z * wb4.z + xb4.w * wb4.w;
    }
  }

  // ---- write act + batch-stat partials ----
  #pragma unroll
  for (int r = 0; r < 4; ++r) {
    const int d = t + 512 * r;
    float s = 0.0f, s2 = 0.0f;
    #pragma unroll
    for (int b = 0; b < 8; ++b) {
      float a = acc[r][b];
      act[(size_t)(b0 + b) * D_ + d] = a;
      s += a;
      s2 = fmaf(a, a, s2);
    }
    atomicAdd(&sums[d], s);
    atomicAdd(&sumsq[d], s2);
  }
}

// ---------- K3: fold BN stats into per-d scale/shift ----------
__global__ __launch_bounds__(256) void finalize_stats(
    const float* __restrict__ sums, const float* __restrict__ sumsq,
    const float* __restrict__ gamma, const float* __restrict__ beta,
    float* __restrict__ scsh)
{
  int d = blockIdx.x * 256 + threadIdx.x;
  if (d < D_) {
    float mean = sums[d]  * (1.0f / B_);
    float var  = sumsq[d] * (1.0f / B_) - mean * mean;
    float rstd = rsqrtf(var + 1e-5f);
    float sc   = gamma[d] * rstd;
    scsh[2 * d]     = sc;
    scsh[2 * d + 1] = fmaf(-mean, sc, beta[d]);
  }
}

// ---------- K4: normalize + sigmoid (in place on d_out) ----------
__global__ __launch_bounds__(256) void norm_sigmoid(
    float* __restrict__ act, const float* __restrict__ scsh)
{
  const int total4 = (B_ * D_) / 4;
  for (int i = blockIdx.x * blockDim.x + threadIdx.x; i < total4;
       i += gridDim.x * blockDim.x) {
    float4 a = reinterpret_cast<float4*>(act)[i];
    int d0 = (i * 4) & (D_ - 1);
    const float4* sp = reinterpret_cast<const float4*>(scsh + 2 * d0);
    float4 s0 = sp[0];   // (sc0, sh0, sc1, sh1)
    float4 s1 = sp[1];   // (sc2, sh2, sc3, sh3)
    float z0 = fmaf(a.x, s0.x, s0.y);
    float z1 = fmaf(a.y, s0.z, s0.w);
    float z2 = fmaf(a.z, s1.x, s1.y);
    float z3 = fmaf(a.w, s1.z, s1.w);
    a.x = 1.0f / (1.0f + __expf(-z0));
    a.y = 1.0f / (1.0f + __expf(-z1));
    a.z = 1.0f / (1.0f + __expf(-z2));
    a.w = 1.0f / (1.0f + __expf(-z3));
    reinterpret_cast<float4*>(act)[i] = a;
  }
}

extern "C" void kernel_launch(void* const* d_in, const int* in_sizes, int n_in,
                              void* d_out, int out_size, void* d_ws, size_t ws_size,
                              hipStream_t stream) {
  const float* xe    = (const float*)d_in[0];
  const float* xi    = (const float*)d_in[1];
  const float* xbr   = (const float*)d_in[2];
  const float* wexc  = (const float*)d_in[3];
  const float* winh  = (const float*)d_in[4];
  const float* wblk  = (const float*)d_in[5];
  const float* gamma = (const float*)d_in[6];
  const float* beta  = (const float*)d_in[7];
  float* act = (float*)d_out;

  char* ws = (char*)d_ws;
  unsigned* so_exc = (unsigned*)(ws + 0);        // 2048*52 u32
  float*    ve_exc = (float*)   (ws + 425984);   // 2048*52 f32
  unsigned* so_inh = (unsigned*)(ws + 851968);   // 2048 u32
  float*    vi_inh = (float*)   (ws + 860160);   // 2048 f32
  float*    sums   = (float*)   (ws + 868352);   // 2048 f32
  float*    sumsq  = (float*)   (ws + 876544);   // 2048 f32  (contiguous w/ sums)
  float*    scsh   = (float*)   (ws + 884736);   // 2048*2 f32

  hipMemsetAsync(sums, 0, 2 * D_ * sizeof(float), stream);

  const float hi = 0.015625f;   // 1/sqrt(4096) fan-in bound
  topk_kernel<<<dim3(D_), dim3(256), 0, stream>>>(
      wexc, KE_, KPAD_, hi, hi * (1.0f - 200.0f / 4096.0f), 1.0f, so_exc, ve_exc);
  topk_kernel<<<dim3(D_), dim3(256), 0, stream>>>(
      winh, 1, 1, hi, hi * (1.0f - 48.0f / 4096.0f), -50.0f, so_inh, vi_inh);
  fused_main<<<dim3(B_ / 8), dim3(512), 0, stream>>>(
      xe, xi, xbr, wblk, so_exc, ve_exc, so_inh, vi_inh, act, sums, sumsq);
  finalize_stats<<<dim3((D_ + 255) / 256), dim3(256), 0, stream>>>(
      sums, sumsq, gamma, beta, scsh);
  norm_sigmoid<<<dim3(2048), dim3(256), 0, stream>>>(act, scsh);
}

// Round 2
// 140.013 us; speedup vs baseline: 1.5188x; 1.5188x over previous
//
#include <hip/hip_runtime.h>
#include <hip/hip_fp16.h>

#define B_     4096
#define INE_   4096
#define INBR_  8192
#define D_     2048
#define KE_    50
#define KPAD_  52
#define CAP_   512

// ---------- helpers ----------
__device__ __forceinline__ unsigned packh2(float a, float b) {
  __half2 h = __floats2half2_rn(a, b);
  return __builtin_bit_cast(unsigned, h);
}
__device__ __forceinline__ float2 unpackh2(unsigned u) {
  __half2 h = __builtin_bit_cast(__half2, u);
  return __half22float2(h);
}

// ---------- K0: extract block-diagonal of w_block into compact [D][4] ----------
__global__ __launch_bounds__(256) void extract_diag(
    const float* __restrict__ wblock, float* __restrict__ wdiag)
{
  int d = blockIdx.x * 256 + threadIdx.x;
  float4 w = *reinterpret_cast<const float4*>(wblock + (size_t)d * (INBR_ + 4));
  reinterpret_cast<float4*>(wdiag)[d] = w;
}

// ---------- K1: exact top-k per row, written by rank (deterministic) ----------
// kpad==KPAD_: transposed layout [13][D][4] for coalesced uint4/float4 loads.
// kpad==1:    flat [D] layout.
__global__ __launch_bounds__(256) void topk_kernel(
    const float* __restrict__ W, int k, int kpad, float hi, float t0,
    float vscale, unsigned* __restrict__ out_off, float* __restrict__ out_val)
{
  const int row = blockIdx.x;
  const int t   = threadIdx.x;
  const float* wr = W + (size_t)row * INE_;

  __shared__ float cval[CAP_];
  __shared__ int   ccol[CAP_];
  __shared__ int   scnt;
  __shared__ int   red[4];

  // ---- threshold search (usually 1 iteration) ----
  float thr = t0;
  int M = 0;
  for (int attempt = 0; attempt < 8; ++attempt) {
    int local = 0;
    #pragma unroll
    for (int j = 0; j < 4; ++j) {
      float4 w4 = *reinterpret_cast<const float4*>(wr + 4 * (t + 256 * j));
      local += (w4.x > thr) + (w4.y > thr) + (w4.z > thr) + (w4.w > thr);
    }
    #pragma unroll
    for (int off = 32; off > 0; off >>= 1) local += __shfl_down(local, off);
    if ((t & 63) == 0) red[t >> 6] = local;
    __syncthreads();
    M = red[0] + red[1] + red[2] + red[3];
    __syncthreads();
    if (M >= k && M <= CAP_) break;
    if (M < k) thr = hi - (hi - thr) * 4.0f;   // widen window downward
    else       thr = hi - (hi - thr) * 0.5f;   // narrow
  }

  // ---- compaction (candidate SET is deterministic; order doesn't matter) ----
  if (t == 0) scnt = 0;
  __syncthreads();
  #pragma unroll
  for (int j = 0; j < 4; ++j) {
    int cbase = 4 * (t + 256 * j);
    float4 w4 = *reinterpret_cast<const float4*>(wr + cbase);
    float wv[4] = {w4.x, w4.y, w4.z, w4.w};
    #pragma unroll
    for (int q = 0; q < 4; ++q) {
      if (wv[q] > thr) {
        int p = atomicAdd(&scnt, 1);
        if (p < CAP_) { cval[p] = wv[q]; ccol[p] = cbase + q; }
      }
    }
  }
  __syncthreads();
  M = scnt < CAP_ ? scnt : CAP_;

  // ---- exact rank among candidates (ties -> lowest column index) ----
  for (int i = t; i < M; i += 256) {
    float wi = cval[i]; int ci = ccol[i];
    int rank = 0;
    for (int m = 0; m < M; ++m) {
      float wm = cval[m]; int cm = ccol[m];
      rank += (wm > wi || (wm == wi && cm < ci)) ? 1 : 0;
    }
    if (rank < k) {
      unsigned c = (unsigned)ci;
      // pre-swizzled LDS byte offset: 16 * s(c), s(c) = (c>>2) | ((c&3)<<10)
      unsigned off = ((c >> 2) << 4) | ((c & 3u) << 14);
      float    val = wi * vscale;
      if (kpad == 1) {
        out_off[row] = off;
        out_val[row] = val;
      } else {
        // slot `rank` -> transposed [rank>>2][row][rank&3]
        size_t idx = ((size_t)(rank >> 2) * D_ + row) * 4 + (rank & 3);
        out_off[idx] = off;
        out_val[idx] = val;
      }
    }
  }
  // ---- pad slots k..kpad-1 with zeros ----
  if (kpad > 1 && t < kpad - k) {
    int slot = k + t;
    size_t idx = ((size_t)(slot >> 2) * D_ + row) * 4 + (slot & 3);
    out_off[idx] = 0u;
    out_val[idx] = 0.0f;
  }
}

// ---------- K2: fused sparse-gather act computation ----------
// LDS layout: column c of the 8 staged rows lives at words [4*s(c) .. 4*s(c)+3],
// word p = half2(row 2p, row 2p+1).  s(c) = (c>>2) | ((c&3)<<10)  (bijective).
__device__ __forceinline__ void stage_rows(const float* __restrict__ src,
                                           unsigned* xs, int b0, int p, int Q) {
  const float* r0p = src + (size_t)(b0 + 2 * p)     * INE_;
  const float* r1p = src + (size_t)(b0 + 2 * p + 1) * INE_;
  #pragma unroll
  for (int m = 0; m < 8; ++m) {
    int c0 = 4 * Q + 512 * m;
    float4 fa = *reinterpret_cast<const float4*>(r0p + c0);
    float4 fb = *reinterpret_cast<const float4*>(r1p + c0);
    int wb = 4 * (Q + 128 * m) + p;
    xs[wb]          = packh2(fa.x, fb.x);
    xs[wb + 4096]   = packh2(fa.y, fb.y);
    xs[wb + 8192]   = packh2(fa.z, fb.z);
    xs[wb + 12288]  = packh2(fa.w, fb.w);
  }
}

#define GATH(R, OFF, WV) do {                                              \
    uint4 xq = *reinterpret_cast<const uint4*>(ldsb + (OFF));              \
    float2 f0 = unpackh2(xq.x), f1 = unpackh2(xq.y);                       \
    float2 f2 = unpackh2(xq.z), f3 = unpackh2(xq.w);                       \
    acc[R][0] = fmaf(f0.x, (WV), acc[R][0]);                               \
    acc[R][1] = fmaf(f0.y, (WV), acc[R][1]);                               \
    acc[R][2] = fmaf(f1.x, (WV), acc[R][2]);                               \
    acc[R][3] = fmaf(f1.y, (WV), acc[R][3]);                               \
    acc[R][4] = fmaf(f2.x, (WV), acc[R][4]);                               \
    acc[R][5] = fmaf(f2.y, (WV), acc[R][5]);                               \
    acc[R][6] = fmaf(f3.x, (WV), acc[R][6]);                               \
    acc[R][7] = fmaf(f3.y, (WV), acc[R][7]);                               \
  } while (0)

__global__ __launch_bounds__(512, 4) void fused_main(
    const float* __restrict__ xe, const float* __restrict__ xi,
    const float* __restrict__ xbr, const float* __restrict__ wdiag,
    const unsigned* __restrict__ soT, const float* __restrict__ veT,
    const unsigned* __restrict__ so_inh, const float* __restrict__ vi_inh,
    float* __restrict__ act)
{
  __shared__ unsigned xs[16384];          // 64 KiB
  const int t  = threadIdx.x;
  const int b0 = blockIdx.x * 8;
  const int p  = t & 3;
  const int Q  = t >> 2;

  float acc[4][8];
  #pragma unroll
  for (int r = 0; r < 4; ++r)
    #pragma unroll
    for (int b = 0; b < 8; ++b) acc[r][b] = 0.0f;

  const char* ldsb = reinterpret_cast<const char*>(xs);
  const uint4*  soT4 = reinterpret_cast<const uint4*>(soT);
  const float4* veT4 = reinterpret_cast<const float4*>(veT);

  // ---- phase E: excitation (top-50 sparse), 4 r-chains interleaved ----
  stage_rows(xe, xs, b0, p, Q);
  __syncthreads();
  for (int ii = 0; ii < KPAD_ / 4; ++ii) {
    uint4 o[4]; float4 v[4];
    #pragma unroll
    for (int r = 0; r < 4; ++r) {
      const int d = t + 512 * r;
      o[r] = soT4[ii * D_ + d];           // coalesced: consecutive t -> consecutive 16B
      v[r] = veT4[ii * D_ + d];
    }
    #pragma unroll
    for (int r = 0; r < 4; ++r) {
      GATH(r, o[r].x, v[r].x);
      GATH(r, o[r].y, v[r].y);
      GATH(r, o[r].z, v[r].z);
      GATH(r, o[r].w, v[r].w);
    }
  }
  __syncthreads();

  // ---- phase I: inhibition (top-1 sparse, value pre-scaled by -50) ----
  stage_rows(xi, xs, b0, p, Q);
  unsigned oi[4]; float vi[4];
  #pragma unroll
  for (int r = 0; r < 4; ++r) {
    const int d = t + 512 * r;
    oi[r] = so_inh[d];
    vi[r] = vi_inh[d];
  }
  __syncthreads();
  #pragma unroll
  for (int r = 0; r < 4; ++r) GATH(r, oi[r], vi[r]);

  // ---- phase BR: block-diagonal depolarization (streamed, coalesced) ----
  #pragma unroll
  for (int r = 0; r < 4; ++r) {
    const int d = t + 512 * r;
    float4 wb4 = reinterpret_cast<const float4*>(wdiag)[d];
    #pragma unroll
    for (int b = 0; b < 8; ++b) {
      float4 xb4 = *reinterpret_cast<const float4*>(
          xbr + (size_t)(b0 + b) * INBR_ + 4 * d);
      acc[r][b] += xb4.x * wb4.x + xb4.y * wb4.y + xb4.z * wb4.z + xb4.w * wb4.w;
    }
  }

  // ---- write act (coalesced) ----
  #pragma unroll
  for (int r = 0; r < 4; ++r) {
    const int d = t + 512 * r;
    #pragma unroll
    for (int b = 0; b < 8; ++b)
      act[(size_t)(b0 + b) * D_ + d] = acc[r][b];
  }
}

// ---------- K3a: column sums/sumsq over act (coalesced, low-contention) ----------
__global__ __launch_bounds__(256) void reduce_stats(
    const float* __restrict__ act, float* __restrict__ sums,
    float* __restrict__ sumsq)
{
  const int dg = blockIdx.x & 63;    // 64 column groups of 32
  const int rg = blockIdx.x >> 6;    // 8 row groups of 512
  const int tx = threadIdx.x & 31;
  const int ty = threadIdx.x >> 5;
  const int d  = dg * 32 + tx;

  float s = 0.0f, s2 = 0.0f;
  #pragma unroll 4
  for (int i = 0; i < 64; ++i) {
    int row = rg * 512 + ty + 8 * i;
    float a = act[(size_t)row * D_ + d];
    s += a;
    s2 = fmaf(a, a, s2);
  }
  __shared__ float ls[2][8][32];
  ls[0][ty][tx] = s;
  ls[1][ty][tx] = s2;
  __syncthreads();
  if (ty == 0) {
    #pragma unroll
    for (int j = 1; j < 8; ++j) { s += ls[0][j][tx]; s2 += ls[1][j][tx]; }
    atomicAdd(&sums[d], s);      // 64 atomics per column total: negligible
    atomicAdd(&sumsq[d], s2);
  }
}

// ---------- K3b: fold BN stats into per-d scale/shift ----------
__global__ __launch_bounds__(256) void finalize_stats(
    const float* __restrict__ sums, const float* __restrict__ sumsq,
    const float* __restrict__ gamma, const float* __restrict__ beta,
    float* __restrict__ scsh)
{
  int d = blockIdx.x * 256 + threadIdx.x;
  if (d < D_) {
    float mean = sums[d]  * (1.0f / B_);
    float var  = sumsq[d] * (1.0f / B_) - mean * mean;
    float rstd = rsqrtf(var + 1e-5f);
    float sc   = gamma[d] * rstd;
    scsh[2 * d]     = sc;
    scsh[2 * d + 1] = fmaf(-mean, sc, beta[d]);
  }
}

// ---------- K4: normalize + sigmoid (in place on d_out) ----------
__global__ __launch_bounds__(256) void norm_sigmoid(
    float* __restrict__ act, const float* __restrict__ scsh)
{
  const int total4 = (B_ * D_) / 4;
  for (int i = blockIdx.x * blockDim.x + threadIdx.x; i < total4;
       i += gridDim.x * blockDim.x) {
    float4 a = reinterpret_cast<float4*>(act)[i];
    int d0 = (i * 4) & (D_ - 1);
    const float4* sp = reinterpret_cast<const float4*>(scsh + 2 * d0);
    float4 s0 = sp[0];   // (sc0, sh0, sc1, sh1)
    float4 s1 = sp[1];   // (sc2, sh2, sc3, sh3)
    float z0 = fmaf(a.x, s0.x, s0.y);
    float z1 = fmaf(a.y, s0.z, s0.w);
    float z2 = fmaf(a.z, s1.x, s1.y);
    float z3 = fmaf(a.w, s1.z, s1.w);
    a.x = 1.0f / (1.0f + __expf(-z0));
    a.y = 1.0f / (1.0f + __expf(-z1));
    a.z = 1.0f / (1.0f + __expf(-z2));
    a.w = 1.0f / (1.0f + __expf(-z3));
    reinterpret_cast<float4*>(act)[i] = a;
  }
}

extern "C" void kernel_launch(void* const* d_in, const int* in_sizes, int n_in,
                              void* d_out, int out_size, void* d_ws, size_t ws_size,
                              hipStream_t stream) {
  const float* xe    = (const float*)d_in[0];
  const float* xi    = (const float*)d_in[1];
  const float* xbr   = (const float*)d_in[2];
  const float* wexc  = (const float*)d_in[3];
  const float* winh  = (const float*)d_in[4];
  const float* wblk  = (const float*)d_in[5];
  const float* gamma = (const float*)d_in[6];
  const float* beta  = (const float*)d_in[7];
  float* act = (float*)d_out;

  char* ws = (char*)d_ws;
  unsigned* soT    = (unsigned*)(ws + 0);        // [13][2048][4] u32 = 425984 B
  float*    veT    = (float*)   (ws + 425984);   // [13][2048][4] f32
  unsigned* so_inh = (unsigned*)(ws + 851968);   // [2048] u32
  float*    vi_inh = (float*)   (ws + 860160);   // [2048] f32
  float*    wdiag  = (float*)   (ws + 868352);   // [2048][4] f32 = 32768 B
  float*    sums   = (float*)   (ws + 901120);   // [2048] f32
  float*    sumsq  = (float*)   (ws + 909312);   // [2048] f32 (contiguous w/ sums)
  float*    scsh   = (float*)   (ws + 917504);   // [2048][2] f32

  hipMemsetAsync(sums, 0, 2 * D_ * sizeof(float), stream);

  const float hi = 0.015625f;   // 1/sqrt(4096) fan-in bound
  extract_diag<<<dim3(8), dim3(256), 0, stream>>>(wblk, wdiag);
  topk_kernel<<<dim3(D_), dim3(256), 0, stream>>>(
      wexc, KE_, KPAD_, hi, hi * (1.0f - 200.0f / 4096.0f), 1.0f, soT, veT);
  topk_kernel<<<dim3(D_), dim3(256), 0, stream>>>(
      winh, 1, 1, hi, hi * (1.0f - 48.0f / 4096.0f), -50.0f, so_inh, vi_inh);
  fused_main<<<dim3(B_ / 8), dim3(512), 0, stream>>>(
      xe, xi, xbr, wdiag, soT, veT, so_inh, vi_inh, act);
  reduce_stats<<<dim3(512), dim3(256), 0, stream>>>(act, sums, sumsq);
  finalize_stats<<<dim3((D_ + 255) / 256), dim3(256), 0, stream>>>(
      sums, sumsq, gamma, beta, scsh);
  norm_sigmoid<<<dim3(2048), dim3(256), 0, stream>>>(act, scsh);
}